// Round 12
// baseline (115.471 us; speedup 1.0000x reference)
//
#include <hip/hip_runtime.h>
#include <math.h>

#define D_MODEL 2048
#define NUM_EXP 64
#define TOKB    8
#define RSTRIDE 2060            // floats per LDS row: 2048 + 12 pad (8240 B)

typedef _Float16 f16x8 __attribute__((ext_vector_type(8)));
typedef float    f32x4 __attribute__((ext_vector_type(4)));

__device__ __forceinline__ void gload16(const void* g, void* l) {
    __builtin_amdgcn_global_load_lds(
        (const __attribute__((address_space(1))) unsigned int*)g,
        (__attribute__((address_space(3))) unsigned int*)l, 16, 0, 0);
}

// ---------------------------------------------------------------------------
// k0: W[64][2048] fp32 -> fragment-linear f16 hi/lo (W = wh + wl*2^-12, wl
// scaled 4096; exact split). Frag (kc, mf): lane l holds
// A[m = mf*16 + (l&15)][k = kc*32 + (l>>4)*8 + j], flat at whf[(kc*4+mf)*64+l].
// ---------------------------------------------------------------------------
__global__ __launch_bounds__(256)
void k0_convw(const float* __restrict__ W, f16x8* __restrict__ whf,
              f16x8* __restrict__ wlf) {
    const int t    = blockIdx.x * 256 + threadIdx.x;
    const int lane = t & 63;
    const int mf   = (t >> 6) & 3;
    const int kc   = t >> 8;
    const int m    = mf * 16 + (lane & 15);
    const int k0   = kc * 32 + ((lane >> 4) << 3);
    const float* src = W + (size_t)m * D_MODEL + k0;
    f16x8 h, l;
#pragma unroll
    for (int j = 0; j < 8; ++j) {
        float v = src[j];
        _Float16 hh = (_Float16)v;
        h[j] = hh;
        l[j] = (_Float16)((v - (float)hh) * 4096.f);
    }
    whf[t] = h;
    wlf[t] = l;
}

// ---------------------------------------------------------------------------
// k1: sequential-DMA fused router. Block = 256 thr (4 waves) = 8 tokens.
// STAGE: wave w streams rows {2w, 2w+1} as 16x 1KB CONTIGUOUS global_load_lds
// (DRAM sees clean sequential bursts -- the m13 pattern; this is the round's
// experiment: every prior structure issued 256B-granule row-scattered reads
// and saturated at ~2.5-3 TB/s effective). One __syncthreads (drain wanted).
// COMPUTE: wave w owns expert-16-group w, all 8 tokens, full K. Per 8-chunk
// phase: 16 batched W-frag loads (L2-resident, f16 frag-linear from k0), then
// per chunk: 2x ds_read_b128 fp32 x-frag (row = lane&7; cols 8-15 of the
// 16-col MFMA B-frag are don't-care), exact fp16 hi/lo cvt, 3 MFMA into one
// f32x4 acc pair (fixed order, full-K -> absmax unchanged).
// Cross-BLOCK overlap does the latency hiding: 70 KB LDS -> 2 blocks/CU;
// block B streams while block A computes. No manual vmcnt anywhere.
// LDS x rows padded +48 B -> bank phase 12/row -> <=4-way ds conflicts.
// Epilogue: ep tile -> softmax + top-2 (lax.top_k tie rule: lower index
// wins) for 2 tokens/wave + per-block expert partials. Deterministic.
// Grid: N/8 = 2048 blocks; 8 waves/CU.
// ---------------------------------------------------------------------------
__global__ __launch_bounds__(256, 2)
void k1_fused(const float* __restrict__ x, const f16x8* __restrict__ whf,
              const f16x8* __restrict__ wlf, float* __restrict__ out,
              float* __restrict__ p_part, float* __restrict__ f_part, int N) {
    const int tid  = threadIdx.x;
    const int lane = tid & 63;
    const int w    = tid >> 6;            // wave = expert 16-group
    const int tok0 = blockIdx.x * TOKB;

    __shared__ float xs[TOKB * RSTRIDE];  // 65,920 B (padded rows)
    __shared__ float ep[TOKB][66];        // 2112 B (padded)
    __shared__ float p_red[4][64], f_red[4][64];

    // --- STAGE: 16x 1KB contiguous DMA per wave (rows 2w, 2w+1) ------------
    {
        const int r0 = w * 2;
#pragma unroll
        for (int i = 0; i < 16; ++i) {
            const int row = r0 + (i & 1);
            const int kq  = i >> 1;       // 1KB chunk within the row
            const float* src = x + (size_t)(tok0 + row) * D_MODEL
                             + kq * 256 + lane * 4;      // per-lane 16B
            gload16(src, (char*)&xs[row * RSTRIDE] + kq * 1024);
        }
    }
    __syncthreads();                      // vmcnt(0) drain intended here

    // --- COMPUTE: 8 phases x 8 chunks --------------------------------------
    f32x4 acc1 = f32x4{0.f, 0.f, 0.f, 0.f};
    f32x4 acc2 = f32x4{0.f, 0.f, 0.f, 0.f};

    const int ft = lane & 15;
    const int fs = lane >> 4;
    const char* xrow = (const char*)&xs[(ft & 7) * RSTRIDE] + fs * 32;

    for (int q = 0; q < 8; ++q) {
        f16x8 wh[8], wl[8];
#pragma unroll
        for (int j = 0; j < 8; ++j) {     // batched: one L2 latency per phase
            const int c = q * 8 + j;
            wh[j] = whf[(size_t)(c * 4 + w) * 64 + lane];
            wl[j] = wlf[(size_t)(c * 4 + w) * 64 + lane];
        }
#pragma unroll
        for (int j = 0; j < 8; ++j) {
            const int c = q * 8 + j;
            const float4 u0 = *(const float4*)(xrow + c * 128);
            const float4 u1 = *(const float4*)(xrow + c * 128 + 16);
            const float v[8] = {u0.x, u0.y, u0.z, u0.w, u1.x, u1.y, u1.z, u1.w};
            f16x8 xh, xl;
#pragma unroll
            for (int e = 0; e < 8; ++e) {
                _Float16 h = (_Float16)v[e];
                xh[e] = h;
                xl[e] = (_Float16)((v[e] - (float)h) * 4096.f);
            }
            acc1 = __builtin_amdgcn_mfma_f32_16x16x32_f16(wh[j], xh, acc1, 0, 0, 0);
            acc2 = __builtin_amdgcn_mfma_f32_16x16x32_f16(wh[j], xl, acc2, 0, 0, 0);
            acc2 = __builtin_amdgcn_mfma_f32_16x16x32_f16(wl[j], xh, acc2, 0, 0, 0);
        }
    }

    // --- epilogue: logits tile (C: col = lane&15 = token, row = fs*4+p) ----
    __syncthreads();                      // xs reads done before ep aliasing? (distinct arrays; barrier orders ep writes below)
    if (ft < TOKB) {
        f32x4 o = acc1 + acc2 * (1.f / 4096.f);
        *(f32x4*)&ep[ft][w * 16 + fs * 4] = o;
    }
    __syncthreads();

    // --- softmax + top-2, 2 tokens per wave (lane == expert) ---------------
    float pacc = 0.f, facc = 0.f;
#pragma unroll
    for (int i = 0; i < 2; ++i) {
        const int tl = w * 2 + i;
        float logit = ep[tl][lane];

        float m = logit;
        for (int off = 32; off; off >>= 1) m = fmaxf(m, __shfl_xor(m, off));
        float p = __expf(logit - m);
        float S = p;
        for (int off = 32; off; off >>= 1) S += __shfl_xor(S, off);
        float prob = p / S;

        float bv = logit; int bi = lane;
        for (int off = 32; off; off >>= 1) {
            float ov = __shfl_xor(bv, off);
            int   oi = __shfl_xor(bi, off);
            if (ov > bv || (ov == bv && oi < bi)) { bv = ov; bi = oi; }
        }
        float cv = (lane == bi) ? -INFINITY : logit;
        int   ci = lane;
        for (int off = 32; off; off >>= 1) {
            float ov = __shfl_xor(cv, off);
            int   oi = __shfl_xor(ci, off);
            if (ov > cv || (ov == cv && oi < ci)) { cv = ov; ci = oi; }
        }

        if (lane == 0) {
            const int gt = tok0 + tl;
            float w0 = 1.f / (1.f + __expf(cv - bv));
            out[(size_t)gt * 2]     = w0;
            out[(size_t)gt * 2 + 1] = 1.f - w0;
            out[(size_t)2 * N + gt * 2]     = (float)bi;
            out[(size_t)2 * N + gt * 2 + 1] = (float)ci;
        }

        pacc += prob;
        facc += (lane == bi ? 1.f : 0.f) + (lane == ci ? 1.f : 0.f);
    }

    p_red[w][lane] = pacc;
    f_red[w][lane] = facc;
    __syncthreads();
    if (w == 0) {
        float sp = p_red[0][lane] + p_red[1][lane] + p_red[2][lane] + p_red[3][lane];
        float sf = f_red[0][lane] + f_red[1][lane] + f_red[2][lane] + f_red[3][lane];
        p_part[(size_t)blockIdx.x * NUM_EXP + lane] = sp;
        f_part[(size_t)blockIdx.x * NUM_EXP + lane] = sf;
    }
}

// ---------------------------------------------------------------------------
// k3: deterministic aux-loss reduction over 2048 per-block partials.
// aux = E * sum_i (f_sum_i / N) * (p_sum_i / N)
// ---------------------------------------------------------------------------
__global__ __launch_bounds__(1024)
void k3_aux(const float* __restrict__ p_part, const float* __restrict__ f_part,
            float* __restrict__ out, int N, int B2) {
    const int lane = threadIdx.x & 63;
    const int wid  = threadIdx.x >> 6;    // 0..15
    float sp = 0.f, sf = 0.f;
    for (int b = wid; b < B2; b += 16) {
        sp += p_part[(size_t)b * NUM_EXP + lane];
        sf += f_part[(size_t)b * NUM_EXP + lane];
    }
    __shared__ float lsp[16][64];
    __shared__ float lsf[16][64];
    lsp[wid][lane] = sp;
    lsf[wid][lane] = sf;
    __syncthreads();
    if (wid == 0) {
        float tsp = 0.f, tsf = 0.f;
#pragma unroll
        for (int q = 0; q < 16; ++q) { tsp += lsp[q][lane]; tsf += lsf[q][lane]; }
        float v = tsp * tsf;
        for (int off = 32; off; off >>= 1) v += __shfl_xor(v, off);
        if (lane == 0)
            out[(size_t)4 * N] = (float)NUM_EXP * v / ((float)N * (float)N);
    }
}

extern "C" void kernel_launch(void* const* d_in, const int* in_sizes, int n_in,
                              void* d_out, int out_size, void* d_ws, size_t ws_size,
                              hipStream_t stream) {
    const float* x = (const float*)d_in[0];
    const float* W = (const float*)d_in[1];
    float* out = (float*)d_out;

    const int N  = in_sizes[0] / D_MODEL;   // 16384
    const int B1 = N / TOKB;                // 2048 blocks

    // ws: [whf 256KB][wlf 256KB][p_part 512KB][f_part 512KB]
    f16x8* whf = (f16x8*)d_ws;
    f16x8* wlf = whf + 16384;
    float* p_part = (float*)(wlf + 16384);
    float* f_part = p_part + (size_t)B1 * NUM_EXP;

    k0_convw<<<64, 256, 0, stream>>>(W, whf, wlf);
    k1_fused<<<B1, 256, 0, stream>>>(x, whf, wlf, out, p_part, f_part, N);
    k3_aux<<<1, 1024, 0, stream>>>(p_part, f_part, out, N, B1);
}

// Round 13
// 69.190 us; speedup vs baseline: 1.6689x; 1.6689x over previous
//
#include <hip/hip_runtime.h>
#include <math.h>

#define D_MODEL 2048
#define NUM_EXP 64

typedef _Float16 f16x8 __attribute__((ext_vector_type(8)));
typedef float    f32x4 __attribute__((ext_vector_type(4)));

// ---------------------------------------------------------------------------
// k0: W[64][2048] fp32 -> fragment-linear f16 hi/lo (W = wh + wl*2^-12, wl
// scaled 4096; exact split). Frag (kc, mf): lane l holds
// A[m = mf*16 + (l&15)][k = kc*32 + (l>>4)*8 + j], flat at whf[(kc*4+mf)*64+l]
// -> k1's W-load is a fully-coalesced 1KB wave read, L2-resident.
// ---------------------------------------------------------------------------
__global__ __launch_bounds__(256)
void k0_convw(const float* __restrict__ W, f16x8* __restrict__ whf,
              f16x8* __restrict__ wlf) {
    const int t    = blockIdx.x * 256 + threadIdx.x;
    const int lane = t & 63;
    const int mf   = (t >> 6) & 3;
    const int kc   = t >> 8;
    const int m    = mf * 16 + (lane & 15);
    const int k0   = kc * 32 + ((lane >> 4) << 3);
    const float* src = W + (size_t)m * D_MODEL + k0;
    f16x8 h, l;
#pragma unroll
    for (int j = 0; j < 8; ++j) {
        float v = src[j];
        _Float16 hh = (_Float16)v;
        h[j] = hh;
        l[j] = (_Float16)((v - (float)hh) * 4096.f);
    }
    whf[t] = h;
    wlf[t] = l;
}

// ---------------------------------------------------------------------------
// k1: reg-direct fused router, TLP-first.
// Block = 256 thr (4 waves) = 16 tokens; wave w = K-quarter ks.
// Wave: 16 tok x 64 exp x 512 k = 16 chunks of 32 k. Per chunk cluster:
// 8 W-frag loads (1KB contiguous, L2-hot) + 2 x float4 loads, ALL pinned live
// with asm "+v" (anti-sink: R5/R9/R12 showed the compiler serializes loads
// when left free) + sched_barrier(0) fence; 2-deep named A/B pipeline (full
// unroll -> static); then once-per-element exact fp16 split cvt + 12 MFMA
// (logits = xh*wh + 2^-12(xh*wl + xl*wh), low terms scaled 2^12).
// acc = 32 VGPR; NO LDS in the main loop, no barriers, no manual vmcnt.
// Epilogue: 16KB swizzled LDS tile, 4-K-slice fixed-order reduce, per-wave
// softmax + top-2 (lax.top_k tie rule: lower index wins), per-block expert
// partials. Grid: N/16 = 1024 blocks (4096 waves); ~3 blocks/CU by VGPR.
// ---------------------------------------------------------------------------
struct Buf {
    f16x8 wh[4], wl[4];
    f32x4 xa, xb;
};

__global__ __launch_bounds__(256, 3)
void k1_fused(const float* __restrict__ x, const f16x8* __restrict__ whf,
              const f16x8* __restrict__ wlf, float* __restrict__ out,
              float* __restrict__ p_part, float* __restrict__ f_part, int N) {
    const int tid  = threadIdx.x;
    const int lane = tid & 63;
    const int w    = tid >> 6;        // K-quarter 0..3
    const int tok0 = blockIdx.x * 16;
    const int ft   = lane & 15;
    const int fs   = lane >> 4;

    const float* xrow = x + (size_t)(tok0 + ft) * D_MODEL + w * 512 + fs * 8;
    const f16x8* wb   = whf + (size_t)(w * 16) * 256 + lane;   // + (c*4+mf)*64
    const f16x8* lb   = wlf + (size_t)(w * 16) * 256 + lane;

    f32x4 acc1[4], acc2[4];
#pragma unroll
    for (int mf = 0; mf < 4; ++mf) {
        acc1[mf] = f32x4{0.f, 0.f, 0.f, 0.f};
        acc2[mf] = f32x4{0.f, 0.f, 0.f, 0.f};
    }

    auto LOADG = [&](int c, Buf& B) {
#pragma unroll
        for (int mf = 0; mf < 4; ++mf) {
            B.wh[mf] = wb[(c * 4 + mf) * 64];
            B.wl[mf] = lb[(c * 4 + mf) * 64];
        }
        B.xa = *(const f32x4*)(xrow + (size_t)c * 32);
        B.xb = *(const f32x4*)(xrow + (size_t)c * 32 + 4);
        // pin every loaded vector live HERE -> the 10 loads stay batched,
        // outstanding together, not sunk to their uses.
#pragma unroll
        for (int mf = 0; mf < 4; ++mf)
            asm volatile("" : "+v"(B.wh[mf]), "+v"(B.wl[mf]));
        asm volatile("" : "+v"(B.xa), "+v"(B.xb));
    };

    auto COMPUTEG = [&](Buf& B) {
        f16x8 xh, xl;
#pragma unroll
        for (int j = 0; j < 4; ++j) {
            _Float16 h = (_Float16)B.xa[j];
            xh[j] = h;
            xl[j] = (_Float16)((B.xa[j] - (float)h) * 4096.f);
        }
#pragma unroll
        for (int j = 0; j < 4; ++j) {
            _Float16 h = (_Float16)B.xb[j];
            xh[4 + j] = h;
            xl[4 + j] = (_Float16)((B.xb[j] - (float)h) * 4096.f);
        }
#pragma unroll
        for (int mf = 0; mf < 4; ++mf) {
            acc1[mf] = __builtin_amdgcn_mfma_f32_16x16x32_f16(B.wh[mf], xh, acc1[mf], 0, 0, 0);
            acc2[mf] = __builtin_amdgcn_mfma_f32_16x16x32_f16(B.wh[mf], xl, acc2[mf], 0, 0, 0);
            acc2[mf] = __builtin_amdgcn_mfma_f32_16x16x32_f16(B.wl[mf], xh, acc2[mf], 0, 0, 0);
        }
    };

    Buf A, B;
    LOADG(0, A);
#pragma unroll
    for (int c = 0; c < 16; ++c) {
        Buf& cur = (c & 1) ? B : A;
        Buf& nxt = (c & 1) ? A : B;
        if (c + 1 < 16) LOADG(c + 1, nxt);
        __builtin_amdgcn_sched_barrier(0);   // next cluster issued before compute
        COMPUTEG(cur);
    }

    // --- epilogue: swizzled partial tile [ks][16 tok][64 exp] --------------
    // C layout: col = lane&15 = token, row = (lane>>4)*4 + p = expert.
    // Swizzle col e ^= (tok&7)<<3 (bits 3-5): write ~4-way once, read clean.
    __shared__ float part[4][16][64];       // 16 KB
    __shared__ float p_red[4][64], f_red[4][64];

#pragma unroll
    for (int mf = 0; mf < 4; ++mf) {
        f32x4 o = acc1[mf] + acc2[mf] * (1.f / 4096.f);
        const int e0 = (mf * 16 + fs * 4) ^ ((ft & 7) << 3);
        *(f32x4*)&part[w][ft][e0] = o;
    }
    __syncthreads();

    // --- reduce 4 K-slices + softmax + top-2, 4 tokens per wave ------------
    float pacc = 0.f, facc = 0.f;
#pragma unroll
    for (int i = 0; i < 4; ++i) {
        const int tl = w * 4 + i;           // 0..15
        const int col = lane ^ ((tl & 7) << 3);
        float logit = part[0][tl][col] + part[1][tl][col]
                    + part[2][tl][col] + part[3][tl][col];

        float m = logit;
        for (int off = 32; off; off >>= 1) m = fmaxf(m, __shfl_xor(m, off));
        float p = __expf(logit - m);
        float S = p;
        for (int off = 32; off; off >>= 1) S += __shfl_xor(S, off);
        float prob = p / S;

        float bv = logit; int bi = lane;
        for (int off = 32; off; off >>= 1) {
            float ov = __shfl_xor(bv, off);
            int   oi = __shfl_xor(bi, off);
            if (ov > bv || (ov == bv && oi < bi)) { bv = ov; bi = oi; }
        }
        float cv = (lane == bi) ? -INFINITY : logit;
        int   ci = lane;
        for (int off = 32; off; off >>= 1) {
            float ov = __shfl_xor(cv, off);
            int   oi = __shfl_xor(ci, off);
            if (ov > cv || (ov == cv && oi < ci)) { cv = ov; ci = oi; }
        }

        if (lane == 0) {
            const int gt = tok0 + tl;
            float w0 = 1.f / (1.f + __expf(cv - bv));
            out[(size_t)gt * 2]     = w0;
            out[(size_t)gt * 2 + 1] = 1.f - w0;
            out[(size_t)2 * N + gt * 2]     = (float)bi;
            out[(size_t)2 * N + gt * 2 + 1] = (float)ci;
        }

        pacc += prob;
        facc += (lane == bi ? 1.f : 0.f) + (lane == ci ? 1.f : 0.f);
    }

    p_red[w][lane] = pacc;
    f_red[w][lane] = facc;
    __syncthreads();
    if (w == 0) {
        float sp = p_red[0][lane] + p_red[1][lane] + p_red[2][lane] + p_red[3][lane];
        float sf = f_red[0][lane] + f_red[1][lane] + f_red[2][lane] + f_red[3][lane];
        p_part[(size_t)blockIdx.x * NUM_EXP + lane] = sp;
        f_part[(size_t)blockIdx.x * NUM_EXP + lane] = sf;
    }
}

// ---------------------------------------------------------------------------
// k3: deterministic aux-loss reduction over 1024 per-block partials.
// aux = E * sum_i (f_sum_i / N) * (p_sum_i / N)
// ---------------------------------------------------------------------------
__global__ __launch_bounds__(1024)
void k3_aux(const float* __restrict__ p_part, const float* __restrict__ f_part,
            float* __restrict__ out, int N, int B2) {
    const int lane = threadIdx.x & 63;
    const int wid  = threadIdx.x >> 6;    // 0..15
    float sp = 0.f, sf = 0.f;
    for (int b = wid; b < B2; b += 16) {
        sp += p_part[(size_t)b * NUM_EXP + lane];
        sf += f_part[(size_t)b * NUM_EXP + lane];
    }
    __shared__ float lsp[16][64];
    __shared__ float lsf[16][64];
    lsp[wid][lane] = sp;
    lsf[wid][lane] = sf;
    __syncthreads();
    if (wid == 0) {
        float tsp = 0.f, tsf = 0.f;
#pragma unroll
        for (int q = 0; q < 16; ++q) { tsp += lsp[q][lane]; tsf += lsf[q][lane]; }
        float v = tsp * tsf;
        for (int off = 32; off; off >>= 1) v += __shfl_xor(v, off);
        if (lane == 0)
            out[(size_t)4 * N] = (float)NUM_EXP * v / ((float)N * (float)N);
    }
}

extern "C" void kernel_launch(void* const* d_in, const int* in_sizes, int n_in,
                              void* d_out, int out_size, void* d_ws, size_t ws_size,
                              hipStream_t stream) {
    const float* x = (const float*)d_in[0];
    const float* W = (const float*)d_in[1];
    float* out = (float*)d_out;

    const int N  = in_sizes[0] / D_MODEL;   // 16384
    const int B1 = N / 16;                  // 1024 blocks

    // ws: [whf 256KB][wlf 256KB][p_part 256KB][f_part 256KB]
    f16x8* whf = (f16x8*)d_ws;
    f16x8* wlf = whf + 16384;
    float* p_part = (float*)(wlf + 16384);
    float* f_part = p_part + (size_t)B1 * NUM_EXP;

    k0_convw<<<64, 256, 0, stream>>>(W, whf, wlf);
    k1_fused<<<B1, 256, 0, stream>>>(x, whf, wlf, out, p_part, f_part, N);
    k3_aux<<<1, 1024, 0, stream>>>(p_part, f_part, out, N, B1);
}